// Round 7
// baseline (396.490 us; speedup 1.0000x reference)
//
#include <hip/hip_runtime.h>
#include <hip/hip_bf16.h>

#define B_ 8
#define S_ 2048
#define H_ 4096
#define D_ 128
#define NS_ 128
#define KS 16            /* split-K for kgemm: KC = 256 h per block */
#define KC (H_ / KS)
#define KSQ 8            /* split-K for qproj */

typedef _Float16 half8 __attribute__((ext_vector_type(8)));
typedef float floatx4 __attribute__((ext_vector_type(4)));

// ---------------------------------------------------------------------------
// R7: single persistent kernel, 3 phases gated by device-scope atomics.
//   phase 0: mask extract (blk 0..7), Wk pack (8..263), RoPE tables (264..271)
//            -> gate prep_cnt == 272
//   phase 1: kgemm main (0..255), q GEMV (256..319)
//            -> per-b gate kgate[b] == 40 (32 main + 8 qproj)
//   phase 2: logit (blk 0..127) + last-block softmax tail (done[b] == 15)
// flags (prep_cnt, kgate[8], done[8]) zeroed by hipMemsetAsync pre-launch.
// Launch bounds (256,2) => >=2 blocks/CU co-resident capacity 512 >= 320,
// so spin-waits cannot deadlock.
// Workspace layout as R6; every element written before read (ws poison 0xAA).
// Bp index: ((g64*2 + k0)*8 + dt)*64 + quad*16 + mrow   (g64 = 64-h chunk)
// ---------------------------------------------------------------------------

__device__ inline void cvt8(const float* x, half8* hi, half8* lo) {
    half8 h, l;
    #pragma unroll
    for (int j = 0; j < 8; ++j) {
        _Float16 hh = (_Float16)x[j];
        h[j] = hh;
        l[j] = (_Float16)(x[j] - (float)hh);
    }
    *hi = h; *lo = l;
}

__device__ inline floatx4 mfma16(half8 a, half8 b, floatx4 c) {
    return __builtin_amdgcn_mfma_f32_16x16x32_f16(a, b, c, 0, 0, 0);
}

__global__ __launch_bounds__(256, 2) void fused_kernel(
    const float* __restrict__ hs, const float* __restrict__ Wk,
    const int* __restrict__ mask,
    const float* __restrict__ Wq, const float* __restrict__ Wr,
    const float* __restrict__ bq, const float* __restrict__ bk,
    const float* __restrict__ br,
    int* __restrict__ idx, half8* __restrict__ Bp_hi, half8* __restrict__ Bp_lo,
    float* __restrict__ k_part, float* __restrict__ v_part,
    float* __restrict__ q_part,
    float4* __restrict__ ktab, float2* __restrict__ qtab,
    float* __restrict__ logits, float* __restrict__ v_red,
    int* __restrict__ flags, float* __restrict__ out)
{
    __shared__ __align__(16) char smem[16384];
    int bid = blockIdx.x;
    int tid = threadIdx.x;
    int* prep_cnt = flags;        // target 272
    int* kgate    = flags + 1;    // [8], target 40
    int* done     = flags + 9;    // [8], target 16

    // ========================= phase 0: prep =========================
    if (bid < 8) {
        // ---- mask extract for b = bid ----
        int b = bid;
        const int* mrow = mask + b * S_;
        int* wsum = (int*)smem;
        int lane = tid & 63, wave = tid >> 6;
        int base = 0;
        for (int c = 0; c < S_ / 256; ++c) {
            int s = c * 256 + tid;
            int mv = mrow[s];
            unsigned long long bal = __ballot(mv != 0);
            int pre = __popcll(bal & ((1ull << lane) - 1ull));
            __syncthreads();
            if (lane == 0) wsum[wave] = __popcll(bal);
            __syncthreads();
            int woff = 0, tot = 0;
            #pragma unroll
            for (int w = 0; w < 4; ++w) { if (w < wave) woff += wsum[w]; tot += wsum[w]; }
            if (mv) idx[b * NS_ + base + woff + pre] = s;
            base += tot;
        }
    } else if (bid < 264) {
        // ---- Wk pack: 1/8 of one 128-h slice per block ----
        int pk  = bid - 8;          // 0..255
        int kc5 = pk >> 3;          // 128-h slice 0..31
        int sub = pk & 7;
        int u   = sub * 256 + tid;  // u = d*16 + hh*8 + z
        int d   = u >> 4;
        int hh  = (u >> 3) & 1;
        int z   = u & 7;
        const float* src = Wk + (size_t)d * H_ + kc5 * 128 + hh * 64 + z * 8;
        int dt = d >> 4, mrow = d & 15;
        float x[8];
        *(float4*)&x[0] = *(const float4*)(src);
        *(float4*)&x[4] = *(const float4*)(src + 4);
        half8 hi, lo; cvt8(x, &hi, &lo);
        int k0 = z >> 2, quad = z & 3;
        int g64 = kc5 * 2 + hh;
        int o = ((g64 * 2 + k0) * 8 + dt) * 64 + quad * 16 + mrow;
        Bp_hi[o] = hi; Bp_lo[o] = lo;
    } else if (bid < 272) {
        // ---- RoPE tables (float, exactly R4 formulas) ----
        int base = (bid - 264) * 512;
        #pragma unroll
        for (int u = 0; u < 2; ++u) {
            int e = base + u * 256 + tid;
            int tg = e >> 5, q4 = e & 31;
            float fr0 = 1.0f / powf(10000.0f, (float)(4 * q4) / 128.0f);
            float fr1 = 1.0f / powf(10000.0f, (float)(4 * q4 + 2) / 128.0f);
            float s0, c0, s1, c1;
            sincosf((float)tg * fr0, &s0, &c0);
            sincosf((float)tg * fr1, &s1, &c1);
            ktab[e] = make_float4(c0, s0, c1, s1);
        }
        if (bid == 264 && tid < 64) {
            float fr = 1.0f / powf(10000.0f, (float)(2 * tid) / 128.0f);
            float s, c;
            sincosf(127.0f * fr, &s, &c);
            qtab[tid] = make_float2(c, s);
        }
    }
    if (bid < 272) {
        __syncthreads();
        if (tid == 0) { __threadfence(); atomicAdd(prep_cnt, 1); }
    }
    if (tid == 0) {
        while (__hip_atomic_load(prep_cnt, __ATOMIC_ACQUIRE, __HIP_MEMORY_SCOPE_AGENT) < 272)
            __builtin_amdgcn_s_sleep(2);
    }
    __syncthreads();

    // ========================= phase 1: kgemm ========================
    if (bid >= 256) {
        // ---- q projection for the last selected token ----
        int qb = bid - 256;
        int b  = qb >> 3;
        int kc = qb & 7;
        float* hsrow = (float*)smem;            // 2 KB
        float* qred  = (float*)(smem + 2048);   // 512 B
        int ilast = idx[b * NS_ + NS_ - 1];
        const float* rp = hs + ((size_t)(b * S_ + ilast)) * H_ + kc * 512;
        if (tid < 128) ((float4*)hsrow)[tid] = ((const float4*)rp)[tid];
        __syncthreads();
        int d = tid & 127, half = tid >> 7;
        const float* wq = Wq + (size_t)d * H_ + kc * 512 + half * 256;
        const float* hh = hsrow + half * 256;
        float acc = 0.f;
        #pragma unroll 8
        for (int h = 0; h < 256; h += 4) {
            float4 w = *(const float4*)(wq + h);
            acc += hh[h] * w.x + hh[h + 1] * w.y + hh[h + 2] * w.z + hh[h + 3] * w.w;
        }
        if (half) qred[d] = acc;
        __syncthreads();
        if (!half) q_part[(kc * B_ + b) * D_ + d] = acc + qred[d];
        __syncthreads();
        if (tid == 0) { __threadfence(); atomicAdd(&kgate[b], 1); }
        return;                                  // qproj blocks are done
    }

    {
        int b  = bid >> 5;           // 0..7
        int kc = (bid >> 1) & 15;    // 0..15 (256-h slice)
        int th = bid & 1;            // token half

        half8* AhS = (half8*)smem;                  // [8 kg][64 tok] : 8 KB
        half8* AlS = (half8*)(smem + 8192);         // 8 KB

        int ia   = tid & 63;
        int half = tid >> 6;
        int row  = idx[b * NS_ + th * 64 + ia];
        const float* ap  = hs + ((size_t)(b * S_ + row)) * H_ + kc * KC;
        const float* wrp = Wr + kc * KC;

        int lane = tid & 63, w = tid >> 6;
        int quad = lane >> 4, mrow = lane & 15;
        int TB = (w >> 1) * 32;
        int DB = (w & 1) * 64;

        floatx4 acc[2][4];
        #pragma unroll
        for (int i = 0; i < 2; ++i)
            #pragma unroll
            for (int j = 0; j < 4; ++j) acc[i][j] = (floatx4){0.f, 0.f, 0.f, 0.f};
        float vacc = 0.f;

        #pragma unroll
        for (int c = 0; c < 4; ++c) {               // four 64-h chunks (KC=256)
            #pragma unroll
            for (int g = 0; g < 2; ++g) {
                float x[8], wv[8];
                *(float4*)&x[0]  = *(const float4*)(ap + c * 64 + half * 16 + g * 8);
                *(float4*)&x[4]  = *(const float4*)(ap + c * 64 + half * 16 + g * 8 + 4);
                *(float4*)&wv[0] = *(const float4*)(wrp + c * 64 + half * 16 + g * 8);
                *(float4*)&wv[4] = *(const float4*)(wrp + c * 64 + half * 16 + g * 8 + 4);
                #pragma unroll
                for (int j = 0; j < 8; ++j) vacc += x[j] * wv[j];
                half8 hi, lo; cvt8(x, &hi, &lo);
                AhS[(half * 2 + g) * 64 + ia] = hi;
                AlS[(half * 2 + g) * 64 + ia] = lo;
            }
            __syncthreads();

            int g64 = kc * 4 + c;
            #pragma unroll
            for (int k0 = 0; k0 < 2; ++k0) {
                int kb = (k0 * 4 + quad) * 64;
                int boff = ((g64 * 2 + k0) * 8 + (DB >> 4)) * 64 + lane;
                half8 ah[2], al[2], bh[4], bl[4];
                #pragma unroll
                for (int i = 0; i < 4; ++i) {
                    bh[i] = Bp_hi[boff + i * 64];
                    bl[i] = Bp_lo[boff + i * 64];
                }
                #pragma unroll
                for (int i = 0; i < 2; ++i) {
                    ah[i] = AhS[kb + TB + i * 16 + mrow];
                    al[i] = AlS[kb + TB + i * 16 + mrow];
                }
                #pragma unroll
                for (int mt = 0; mt < 2; ++mt)
                    #pragma unroll
                    for (int nt = 0; nt < 4; ++nt) {
                        acc[mt][nt] = mfma16(ah[mt], bh[nt], acc[mt][nt]);
                        acc[mt][nt] = mfma16(ah[mt], bl[nt], acc[mt][nt]);
                        acc[mt][nt] = mfma16(al[mt], bh[nt], acc[mt][nt]);
                    }
            }
            __syncthreads();
        }

        // ---- epilogue: k_part [b][tok][kc][d] ----
        #pragma unroll
        for (int mt = 0; mt < 2; ++mt)
            #pragma unroll
            for (int nt = 0; nt < 4; ++nt)
                #pragma unroll
                for (int r = 0; r < 4; ++r) {
                    int tok = TB + mt * 16 + quad * 4 + r;
                    int d   = DB + nt * 16 + mrow;
                    int tg  = th * 64 + tok;
                    k_part[(((size_t)(b * NS_ + tg)) * KS + kc) * D_ + d] = acc[mt][nt][r];
                }

        // ---- v reduce ----
        float* vb = (float*)smem;
        vb[half * 64 + ia] = vacc;
        __syncthreads();
        if (tid < 64)
            v_part[(kc * B_ + b) * NS_ + th * 64 + tid] =
                vb[tid] + vb[64 + tid] + vb[128 + tid] + vb[192 + tid];
        __syncthreads();
        if (tid == 0) { __threadfence(); atomicAdd(&kgate[b], 1); }
    }

    if (bid >= 128) return;

    // ========================= phase 2: logit ========================
    int b  = bid >> 4;
    int tc = bid & 15;
    if (tid == 0) {
        while (__hip_atomic_load(&kgate[b], __ATOMIC_ACQUIRE, __HIP_MEMORY_SCOPE_AGENT) < 40)
            __builtin_amdgcn_s_sleep(2);
    }
    __syncthreads();

    float (*qtmp)[D_]  = (float(*)[D_])smem;          // 1 KB
    float*  qr         = (float*)(smem + 1024);       // 512 B
    float (*lred)[32]  = (float(*)[32])(smem + 1536); // 1 KB
    float*  sred       = (float*)(smem + 2560);       // 512 B
    float*  svsh       = (float*)(smem + 3072);       // 512 B
    int*    lastf      = (int*)(smem + 3584);

    {
        int d = tid & 127, hf = tid >> 7;
        float qv = hf ? 0.f : bq[d];
        #pragma unroll
        for (int kc = 0; kc < 4; ++kc) qv += q_part[((hf * 4 + kc) * B_ + b) * D_ + d];
        qtmp[hf][d] = qv;
    }
    int vt = (tid >> 4) & 7, vkc = tid & 15;
    float vv = 0.f;
    if (tid < 128) vv = v_part[(vkc * B_ + b) * NS_ + tc * 8 + vt];
    __syncthreads();

    if (tid < 128) {
        int i = tid >> 1;
        float x0 = qtmp[0][2 * i] + qtmp[1][2 * i];
        float x1 = qtmp[0][2 * i + 1] + qtmp[1][2 * i + 1];
        float2 qt = qtab[i];
        qr[tid] = (tid & 1) ? (x0 * qt.y + x1 * qt.x) : (x0 * qt.x - x1 * qt.y);
        lred[vt][vkc] = vv;
    }
    __syncthreads();
    if (tid < 8) {
        float s = br[0];
        #pragma unroll
        for (int j = 0; j < 16; ++j) s += lred[tid][j];
        v_red[b * NS_ + tc * 8 + tid] = s;
    }

    int tok = tid >> 5, q4 = tid & 31;
    int tg  = tc * 8 + tok;
    float4 kv = make_float4(0.f, 0.f, 0.f, 0.f);
    #pragma unroll 8
    for (int kc = 0; kc < KS; ++kc) {
        float4 x = *(const float4*)(k_part + (((size_t)(b * NS_ + tg)) * KS + kc) * D_ + q4 * 4);
        kv.x += x.x; kv.y += x.y; kv.z += x.z; kv.w += x.w;
    }
    kv.x += bk[4 * q4 + 0]; kv.y += bk[4 * q4 + 1];
    kv.z += bk[4 * q4 + 2]; kv.w += bk[4 * q4 + 3];
    float4 t4 = ktab[tg * 32 + q4];
    float k0 = kv.x * t4.x - kv.y * t4.y;
    float k1 = kv.x * t4.y + kv.y * t4.x;
    float k2 = kv.z * t4.z - kv.w * t4.w;
    float k3 = kv.z * t4.w + kv.w * t4.z;
    float part = k0 * qr[4 * q4] + k1 * qr[4 * q4 + 1]
               + k2 * qr[4 * q4 + 2] + k3 * qr[4 * q4 + 3];
    __syncthreads();
    lred[tok][q4] = part;
    __syncthreads();
    if (tid < 8) {
        float s = 0.f;
        #pragma unroll
        for (int j = 0; j < 32; ++j) s += lred[tid][j];
        logits[b * NS_ + tc * 8 + tid] = s * 0.08838834764831845f;
    }

    // ---- softmax tail: last-arriving block of this b ----
    if (tid < 8) __threadfence();
    __syncthreads();
    if (tid == 0) *lastf = (atomicAdd(&done[b], 1) == 15) ? 1 : 0;
    __syncthreads();
    if (!*lastf) return;
    __threadfence();

    int t = tid & 127;
    float lg = 0.f, vr = 0.f;
    if (tid < 128) {
        lg = __hip_atomic_load(&logits[b * NS_ + t], __ATOMIC_RELAXED, __HIP_MEMORY_SCOPE_AGENT);
        vr = __hip_atomic_load(&v_red [b * NS_ + t], __ATOMIC_RELAXED, __HIP_MEMORY_SCOPE_AGENT);
        sred[t] = lg; svsh[t] = vr;
    }
    __syncthreads();
    float sr = 0.f;
    if (tid < 128) sr = (t == 0) ? svsh[0] : svsh[t] - svsh[t - 1];
    #pragma unroll
    for (int off = 64; off > 0; off >>= 1) {
        if (tid < off) sred[tid] = fmaxf(sred[tid], sred[tid + off]);
        __syncthreads();
    }
    float mx = sred[0];
    __syncthreads();
    float e = 0.f;
    if (tid < 128) { e = expf(lg - mx); sred[t] = e; }
    __syncthreads();
    #pragma unroll
    for (int off = 64; off > 0; off >>= 1) {
        if (tid < off) sred[tid] += sred[tid + off];
        __syncthreads();
    }
    float total = sred[0];
    __syncthreads();
    if (tid < 128) {
        float attn = e / total;
        out[b * NS_ + t] = sr * attn;
        svsh[t] = sr * attn;
    }
    __syncthreads();
    #pragma unroll
    for (int off = 64; off > 0; off >>= 1) {
        if (tid < off) svsh[tid] += svsh[tid + off];
        __syncthreads();
    }
    if (tid == 0) out[B_ * NS_ + b] = svsh[0];
}

extern "C" void kernel_launch(void* const* d_in, const int* in_sizes, int n_in,
                              void* d_out, int out_size, void* d_ws, size_t ws_size,
                              hipStream_t stream) {
    const float* hs   = (const float*)d_in[0];
    const int*   mask = (const int*)d_in[1];
    const float* Wq = (const float*)d_in[3];
    const float* bq = (const float*)d_in[4];
    const float* Wk = (const float*)d_in[5];
    const float* bk = (const float*)d_in[6];
    const float* Wr = (const float*)d_in[7];
    const float* br = (const float*)d_in[8];
    float* out = (float*)d_out;

    char* wsb = (char*)d_ws;
    int*    idx    = (int*)wsb;                              // 4 KB
    half8*  Bp_hi  = (half8*)(wsb + 4096);                   // 1 MB
    half8*  Bp_lo  = (half8*)(wsb + 4096 + 1048576);         // 1 MB
    float*  k_part = (float*)(wsb + 2101248);                // 8 MB [b][tok][kc][d]
    float*  q_part = k_part + (size_t)B_ * NS_ * KS * D_;    // 32 KB
    float*  v_part = q_part + (size_t)KSQ * B_ * D_;         // 64 KB
    float*  logits = v_part + (size_t)KS * B_ * NS_;         // 4 KB
    float*  v_red  = logits + B_ * NS_;                      // 4 KB
    float4* ktab   = (float4*)(v_red + B_ * NS_);            // 64 KB
    float2* qtab   = (float2*)(ktab + NS_ * 32);             // 512 B
    int*    flags  = (int*)(qtab + 64);                      // 17 ints

    hipMemsetAsync(flags, 0, 128, stream);
    fused_kernel<<<320, 256, 0, stream>>>(hs, Wk, mask, Wq, Wr, bq, bk, br,
                                          idx, Bp_hi, Bp_lo, k_part, v_part, q_part,
                                          ktab, qtab, logits, v_red, flags, out);
}

// Round 9
// 337.772 us; speedup vs baseline: 1.1738x; 1.1738x over previous
//
#include <hip/hip_runtime.h>
#include <hip/hip_bf16.h>

#define B_ 8
#define S_ 2048
#define H_ 4096
#define D_ 128
#define NS_ 128
#define KS 16            /* split-K for kgemm: KC = 256 h per block */
#define KC (H_ / KS)
#define KSQ 8            /* split-K for qproj */

typedef _Float16 half8 __attribute__((ext_vector_type(8)));
typedef float floatx4 __attribute__((ext_vector_type(4)));

// ---------------------------------------------------------------------------
// Workspace (byte offsets):
//   idx    : int[1024]             @ 0         (4 KB)
//   Bp_hi  : half8[65536]          @ 4096      (1 MB)  Wk in MFMA-frag order
//   Bp_lo  : half8[65536]          @ 1052672   (1 MB)
//   k_part : float[B][NS][KS][D]   @ 2101248   (8 MB)  [b][tok][kc][d]
//   q_part : float[KSQ][B][D]
//   v_part : float[KS][B][NS]
//   logits : float[B][NS], v_red : float[B][NS]
//   ktab   : float4[NS][32]  (64 KB)  (c0,s0,c1,s1) for token tg, d-group q4
//   qtab   : float2[64]               (c,s) for q RoPE at pos 127
//   done   : int[8]                   inter-block softmax-tail counters
// every element written before read (ws poisoned 0xAA; prep zeroes done[]).
// Bp index: ((g64*2 + k0)*8 + dt)*64 + quad*16 + mrow   (g64 = 64-h chunk 0..63)
//
// R8 = R6 revert (best verified structure). R7's persistent-kernel fusion
// regressed +58us: ACQUIRE spin-polls emit buffer_inv per poll (L2
// invalidate storm during kgemm's L2-hot Bp reads) and per-block release
// fences force eager L2 writebacks; kernel boundaries amortize that
// coherence work once per phase at ~3us each.
// ---------------------------------------------------------------------------

__device__ inline void cvt8(const float* x, half8* hi, half8* lo) {
    half8 h, l;
    #pragma unroll
    for (int j = 0; j < 8; ++j) {
        _Float16 hh = (_Float16)x[j];
        h[j] = hh;
        l[j] = (_Float16)(x[j] - (float)hh);
    }
    *hi = h; *lo = l;
}

__device__ inline floatx4 mfma16(half8 a, half8 b, floatx4 c) {
    return __builtin_amdgcn_mfma_f32_16x16x32_f16(a, b, c, 0, 0, 0);
}

// Kernel 1: blocks 0..7    : extract per-row sorted positions of mask==1.
//           blocks 8..263  : pre-convert+pack Wk into frag-ordered f16 hi/lo.
//           blocks 264..271: RoPE tables (float, 512 entries each);
//                            block 264 also fills qtab + zeroes done[].
__global__ __launch_bounds__(256) void prep_kernel(
    const float* __restrict__ Wk, const int* __restrict__ mask,
    int* __restrict__ idx, half8* __restrict__ Bp_hi, half8* __restrict__ Bp_lo,
    float4* __restrict__ ktab, float2* __restrict__ qtab, int* __restrict__ done)
{
    int bid = blockIdx.x;
    int tid = threadIdx.x;
    if (bid >= 264) {
        // ---- RoPE tables: ktab[tg][q4] = (cos,sin) pairs for fr0, fr1 ----
        int base = (bid - 264) * 512;
        #pragma unroll
        for (int u = 0; u < 2; ++u) {
            int e = base + u * 256 + tid;
            int tg = e >> 5, q4 = e & 31;
            float fr0 = 1.0f / powf(10000.0f, (float)(4 * q4) / 128.0f);
            float fr1 = 1.0f / powf(10000.0f, (float)(4 * q4 + 2) / 128.0f);
            float s0, c0, s1, c1;
            sincosf((float)tg * fr0, &s0, &c0);
            sincosf((float)tg * fr1, &s1, &c1);
            ktab[e] = make_float4(c0, s0, c1, s1);
        }
        if (bid == 264) {
            if (tid < 64) {
                float fr = 1.0f / powf(10000.0f, (float)(2 * tid) / 128.0f);
                float s, c;
                sincosf(127.0f * fr, &s, &c);
                qtab[tid] = make_float2(c, s);
            }
            if (tid < 8) done[tid] = 0;
        }
        return;
    }
    if (bid >= 8) {
        // ---- Wk pack: 1/8 of one 128-h slice per block ----
        int pk  = bid - 8;          // 0..255
        int kc5 = pk >> 3;          // 128-h slice 0..31
        int sub = pk & 7;
        int u   = sub * 256 + tid;  // unit in [0,2048): u = d*16 + hh*8 + z
        int d   = u >> 4;
        int hh  = (u >> 3) & 1;
        int z   = u & 7;
        const float* src = Wk + (size_t)d * H_ + kc5 * 128 + hh * 64 + z * 8;
        int dt = d >> 4, mrow = d & 15;
        float x[8];
        *(float4*)&x[0] = *(const float4*)(src);
        *(float4*)&x[4] = *(const float4*)(src + 4);
        half8 hi, lo; cvt8(x, &hi, &lo);
        int k0 = z >> 2, quad = z & 3;
        int g64 = kc5 * 2 + hh;     // global 64-h chunk 0..63
        int o = ((g64 * 2 + k0) * 8 + dt) * 64 + quad * 16 + mrow;
        Bp_hi[o] = hi; Bp_lo[o] = lo;
        return;
    }
    int b = bid;
    const int* mrow = mask + b * S_;
    __shared__ int wsum[4];
    int lane = tid & 63, wave = tid >> 6;
    int base = 0;
    for (int c = 0; c < S_ / 256; ++c) {
        int s = c * 256 + tid;
        int mv = mrow[s];
        unsigned long long bal = __ballot(mv != 0);
        int pre = __popcll(bal & ((1ull << lane) - 1ull));
        __syncthreads();
        if (lane == 0) wsum[wave] = __popcll(bal);
        __syncthreads();
        int woff = 0, tot = 0;
        #pragma unroll
        for (int w = 0; w < 4; ++w) { if (w < wave) woff += wsum[w]; tot += wsum[w]; }
        if (mv) idx[b * NS_ + base + woff + pre] = s;
        base += tot;
    }
}

// Kernel 2: blocks 0..255: gathered K-projection via f16x3 MFMA, split-K 16,
//           token-split 2 (64 tokens per block), B-frags direct from
//           pre-packed global (no LDS), exact-fp32 v-projection folded in.
//           Blocks 256..319: q GEMV (split-K 8).
__global__ __launch_bounds__(256) void kgemm_kernel(
    const float* __restrict__ hs,
    const half8* __restrict__ Bp_hi, const half8* __restrict__ Bp_lo,
    const float* __restrict__ Wq, const float* __restrict__ Wr,
    const int* __restrict__ idx,
    float* __restrict__ k_part, float* __restrict__ v_part,
    float* __restrict__ q_part)
{
    __shared__ __align__(16) char smem[16384];
    int tid = threadIdx.x;
    int bid = blockIdx.x;

    if (bid >= 256) {
        // ---- q projection for the last selected token ----
        int qb = bid - 256;
        int b  = qb >> 3;
        int kc = qb & 7;
        float* hsrow = (float*)smem;            // 2 KB
        float* qred  = (float*)(smem + 2048);   // 512 B
        int ilast = idx[b * NS_ + NS_ - 1];
        const float* rp = hs + ((size_t)(b * S_ + ilast)) * H_ + kc * 512;
        if (tid < 128) ((float4*)hsrow)[tid] = ((const float4*)rp)[tid];
        __syncthreads();
        int d = tid & 127, half = tid >> 7;
        const float* wq = Wq + (size_t)d * H_ + kc * 512 + half * 256;
        const float* hh = hsrow + half * 256;
        float acc = 0.f;
        #pragma unroll 8
        for (int h = 0; h < 256; h += 4) {
            float4 w = *(const float4*)(wq + h);
            acc += hh[h] * w.x + hh[h + 1] * w.y + hh[h + 2] * w.z + hh[h + 3] * w.w;
        }
        if (half) qred[d] = acc;
        __syncthreads();
        if (!half) q_part[(kc * B_ + b) * D_ + d] = acc + qred[d];
        return;
    }

    int b  = bid >> 5;           // 0..7
    int kc = (bid >> 1) & 15;    // 0..15 (256-h slice)
    int th = bid & 1;            // token half: 0 -> tokens 0..63, 1 -> 64..127

    half8* AhS = (half8*)smem;                  // [8 kg][64 tok] : 8 KB
    half8* AlS = (half8*)(smem + 8192);         // 8 KB

    int ia   = tid & 63;         // token within half (0..63)
    int half = tid >> 6;         // 0..3 : 16-float segment of each 64-h chunk
    int row  = idx[b * NS_ + th * 64 + ia];
    const float* ap  = hs + ((size_t)(b * S_ + row)) * H_ + kc * KC;
    const float* wrp = Wr + kc * KC;

    int lane = tid & 63, w = tid >> 6;
    int quad = lane >> 4, mrow = lane & 15;
    int TB = (w >> 1) * 32;      // wave token base (0 or 32)
    int DB = (w & 1) * 64;       // wave d base

    floatx4 acc[2][4];
    #pragma unroll
    for (int i = 0; i < 2; ++i)
        #pragma unroll
        for (int j = 0; j < 4; ++j) acc[i][j] = (floatx4){0.f, 0.f, 0.f, 0.f};
    float vacc = 0.f;

    #pragma unroll
    for (int c = 0; c < 4; ++c) {               // four 64-h chunks (KC=256)
        // ---- stage A (hi/lo f16) + exact v partial ----
        #pragma unroll
        for (int g = 0; g < 2; ++g) {
            float x[8], wv[8];
            *(float4*)&x[0]  = *(const float4*)(ap + c * 64 + half * 16 + g * 8);
            *(float4*)&x[4]  = *(const float4*)(ap + c * 64 + half * 16 + g * 8 + 4);
            *(float4*)&wv[0] = *(const float4*)(wrp + c * 64 + half * 16 + g * 8);
            *(float4*)&wv[4] = *(const float4*)(wrp + c * 64 + half * 16 + g * 8 + 4);
            #pragma unroll
            for (int j = 0; j < 8; ++j) vacc += x[j] * wv[j];
            half8 hi, lo; cvt8(x, &hi, &lo);
            AhS[(half * 2 + g) * 64 + ia] = hi;
            AlS[(half * 2 + g) * 64 + ia] = lo;
        }
        __syncthreads();

        // ---- MFMA: per k0, A-frags from LDS, B-frags direct from global ----
        int g64 = kc * 4 + c;    // global 64-h chunk
        #pragma unroll
        for (int k0 = 0; k0 < 2; ++k0) {
            int kb = (k0 * 4 + quad) * 64;
            int boff = ((g64 * 2 + k0) * 8 + (DB >> 4)) * 64 + lane;
            half8 ah[2], al[2], bh[4], bl[4];
            #pragma unroll
            for (int i = 0; i < 4; ++i) {
                bh[i] = Bp_hi[boff + i * 64];
                bl[i] = Bp_lo[boff + i * 64];
            }
            #pragma unroll
            for (int i = 0; i < 2; ++i) {
                ah[i] = AhS[kb + TB + i * 16 + mrow];
                al[i] = AlS[kb + TB + i * 16 + mrow];
            }
            #pragma unroll
            for (int mt = 0; mt < 2; ++mt)
                #pragma unroll
                for (int nt = 0; nt < 4; ++nt) {
                    acc[mt][nt] = mfma16(ah[mt], bh[nt], acc[mt][nt]);
                    acc[mt][nt] = mfma16(ah[mt], bl[nt], acc[mt][nt]);
                    acc[mt][nt] = mfma16(al[mt], bh[nt], acc[mt][nt]);
                }
        }
        __syncthreads();
    }

    // ---- epilogue: write k_part [b][tok][kc][d] per C/D mapping ----
    #pragma unroll
    for (int mt = 0; mt < 2; ++mt)
        #pragma unroll
        for (int nt = 0; nt < 4; ++nt)
            #pragma unroll
            for (int r = 0; r < 4; ++r) {
                int tok = TB + mt * 16 + quad * 4 + r;
                int d   = DB + nt * 16 + mrow;
                int tg  = th * 64 + tok;
                k_part[(((size_t)(b * NS_ + tg)) * KS + kc) * D_ + d] = acc[mt][nt][r];
            }

    // ---- v reduce (reuse smem; frag reads are behind the last barrier) ----
    float* vb = (float*)smem;
    vb[half * 64 + ia] = vacc;
    __syncthreads();
    if (tid < 64)
        v_part[(kc * B_ + b) * NS_ + th * 64 + tid] =
            vb[tid] + vb[64 + tid] + vb[128 + tid] + vb[192 + tid];
}

// Kernel 3: per (b, 8-token chunk): reduce q/k/v partials, table-RoPE, logits;
//           the last block per b (device-scope atomic counter) runs the
//           softmax + first-difference tail and writes the outputs.
__global__ __launch_bounds__(256) void logit_kernel(
    const float* __restrict__ k_part, const float* __restrict__ q_part,
    const float* __restrict__ v_part,
    const float* __restrict__ bq, const float* __restrict__ bk,
    const float* __restrict__ br,
    const float4* __restrict__ ktab, const float2* __restrict__ qtab,
    float* __restrict__ logits, float* __restrict__ v_red,
    int* __restrict__ done, float* __restrict__ out)
{
    int b  = blockIdx.x >> 4;
    int tc = blockIdx.x & 15;
    int tid = threadIdx.x;
    __shared__ float qtmp[2][D_];
    __shared__ float qr[D_];
    __shared__ float lred[8][32];
    __shared__ float sred[128];
    __shared__ float svsh[128];
    __shared__ int lastf;

    {
        int d = tid & 127, hf = tid >> 7;
        float qv = hf ? 0.f : bq[d];
        #pragma unroll
        for (int kc = 0; kc < 4; ++kc) qv += q_part[((hf * 4 + kc) * B_ + b) * D_ + d];
        qtmp[hf][d] = qv;
    }
    int vt = (tid >> 4) & 7, vkc = tid & 15;
    float vv = 0.f;
    if (tid < 128) vv = v_part[(vkc * B_ + b) * NS_ + tc * 8 + vt];
    __syncthreads();

    if (tid < 128) {
        int i = tid >> 1;
        float x0 = qtmp[0][2 * i] + qtmp[1][2 * i];
        float x1 = qtmp[0][2 * i + 1] + qtmp[1][2 * i + 1];
        float2 qt = qtab[i];
        qr[tid] = (tid & 1) ? (x0 * qt.y + x1 * qt.x) : (x0 * qt.x - x1 * qt.y);
        lred[vt][vkc] = vv;
    }
    __syncthreads();
    if (tid < 8) {
        float s = br[0];
        #pragma unroll
        for (int j = 0; j < 16; ++j) s += lred[tid][j];
        v_red[b * NS_ + tc * 8 + tid] = s;
    }

    int tok = tid >> 5, q4 = tid & 31;
    int tg  = tc * 8 + tok;
    float4 kv = make_float4(0.f, 0.f, 0.f, 0.f);
    #pragma unroll 8
    for (int kc = 0; kc < KS; ++kc) {
        float4 x = *(const float4*)(k_part + (((size_t)(b * NS_ + tg)) * KS + kc) * D_ + q4 * 4);
        kv.x += x.x; kv.y += x.y; kv.z += x.z; kv.w += x.w;
    }
    kv.x += bk[4 * q4 + 0]; kv.y += bk[4 * q4 + 1];
    kv.z += bk[4 * q4 + 2]; kv.w += bk[4 * q4 + 3];
    float4 t4 = ktab[tg * 32 + q4];
    float k0 = kv.x * t4.x - kv.y * t4.y;
    float k1 = kv.x * t4.y + kv.y * t4.x;
    float k2 = kv.z * t4.z - kv.w * t4.w;
    float k3 = kv.z * t4.w + kv.w * t4.z;
    float part = k0 * qr[4 * q4] + k1 * qr[4 * q4 + 1]
               + k2 * qr[4 * q4 + 2] + k3 * qr[4 * q4 + 3];
    __syncthreads();
    lred[tok][q4] = part;
    __syncthreads();
    if (tid < 8) {
        float s = 0.f;
        #pragma unroll
        for (int j = 0; j < 32; ++j) s += lred[tid][j];
        logits[b * NS_ + tc * 8 + tid] = s * 0.08838834764831845f;
    }

    // ---- softmax tail: last-arriving block of this b does the reduction ----
    if (tid < 8) __threadfence();       // order this thread's logits/v_red stores
    __syncthreads();
    if (tid == 0) lastf = (atomicAdd(&done[b], 1) == 15) ? 1 : 0;
    __syncthreads();
    if (!lastf) return;
    __threadfence();                    // acquire side

    int t = tid & 127;
    float lg = 0.f, vr = 0.f;
    if (tid < 128) {
        lg = __hip_atomic_load(&logits[b * NS_ + t], __ATOMIC_RELAXED, __HIP_MEMORY_SCOPE_AGENT);
        vr = __hip_atomic_load(&v_red [b * NS_ + t], __ATOMIC_RELAXED, __HIP_MEMORY_SCOPE_AGENT);
        sred[t] = lg; svsh[t] = vr;
    }
    __syncthreads();
    float sr = 0.f;
    if (tid < 128) sr = (t == 0) ? svsh[0] : svsh[t] - svsh[t - 1];
    #pragma unroll
    for (int off = 64; off > 0; off >>= 1) {
        if (tid < off) sred[tid] = fmaxf(sred[tid], sred[tid + off]);
        __syncthreads();
    }
    float mx = sred[0];
    __syncthreads();
    float e = 0.f;
    if (tid < 128) { e = expf(lg - mx); sred[t] = e; }
    __syncthreads();
    #pragma unroll
    for (int off = 64; off > 0; off >>= 1) {
        if (tid < off) sred[tid] += sred[tid + off];
        __syncthreads();
    }
    float total = sred[0];
    __syncthreads();
    if (tid < 128) {
        float attn = e / total;
        out[b * NS_ + t] = sr * attn;
        svsh[t] = sr * attn;
    }
    __syncthreads();
    #pragma unroll
    for (int off = 64; off > 0; off >>= 1) {
        if (tid < off) svsh[tid] += svsh[tid + off];
        __syncthreads();
    }
    if (tid == 0) out[B_ * NS_ + b] = svsh[0];
}

extern "C" void kernel_launch(void* const* d_in, const int* in_sizes, int n_in,
                              void* d_out, int out_size, void* d_ws, size_t ws_size,
                              hipStream_t stream) {
    const float* hs   = (const float*)d_in[0];
    const int*   mask = (const int*)d_in[1];
    const float* Wq = (const float*)d_in[3];
    const float* bq = (const float*)d_in[4];
    const float* Wk = (const float*)d_in[5];
    const float* bk = (const float*)d_in[6];
    const float* Wr = (const float*)d_in[7];
    const float* br = (const float*)d_in[8];
    float* out = (float*)d_out;

    char* wsb = (char*)d_ws;
    int*    idx    = (int*)wsb;                              // 4 KB
    half8*  Bp_hi  = (half8*)(wsb + 4096);                   // 1 MB
    half8*  Bp_lo  = (half8*)(wsb + 4096 + 1048576);         // 1 MB
    float*  k_part = (float*)(wsb + 2101248);                // 8 MB [b][tok][kc][d]
    float*  q_part = k_part + (size_t)B_ * NS_ * KS * D_;    // 32 KB
    float*  v_part = q_part + (size_t)KSQ * B_ * D_;         // 64 KB
    float*  logits = v_part + (size_t)KS * B_ * NS_;         // 4 KB
    float*  v_red  = logits + B_ * NS_;                      // 4 KB
    float4* ktab   = (float4*)(v_red + B_ * NS_);            // 64 KB
    float2* qtab   = (float2*)(ktab + NS_ * 32);             // 512 B
    int*    done   = (int*)(qtab + 64);                      // 32 B

    prep_kernel <<<272, 256, 0, stream>>>(Wk, mask, idx, Bp_hi, Bp_lo, ktab, qtab, done);
    kgemm_kernel<<<320, 256, 0, stream>>>(hs, Bp_hi, Bp_lo, Wq, Wr, idx, k_part, v_part, q_part);
    logit_kernel<<<128, 256, 0, stream>>>(k_part, q_part, v_part, bq, bk, br,
                                          ktab, qtab, logits, v_red, done, out);
}